// Round 1
// baseline (155.639 us; speedup 1.0000x reference)
//
#include <hip/hip_runtime.h>
#include <math.h>

#define T_BOX 100
#define NCLS 80
constexpr float EPSF = 1e-7f;
constexpr float INV416 = 1.0f / 416.0f;

__device__ __forceinline__ float sigmoidf_(float x) {
    return 1.0f / (1.0f + __expf(-x));
}

__device__ __forceinline__ float softplus_abs_(float x) {
    // log1p(exp(-|x|))
    return log1pf(__expf(-fabsf(x)));
}

__device__ __forceinline__ float waveReduceAdd(float v) {
    #pragma unroll
    for (int o = 32; o > 0; o >>= 1) v += __shfl_down(v, o);
    return v;
}

// One thread per cell (h, w, anchor). Grid: (ceil(H*W*3/256), B).
__global__ __launch_bounds__(256) void yolo_level_kernel(
    const float* __restrict__ pred,   // (B,H,W,255)
    const float* __restrict__ mask,   // (B,H,W,3,100)
    const float* __restrict__ cls,    // (B,H,W,3,80)
    const float* __restrict__ ytrue,  // (B,100,4)
    float* __restrict__ acc,          // 3 floats: loc, conf, cls sums (undivided)
    int H, int W,
    float aw0, float ah0, float aw1, float ah1, float aw2, float ah2)
{
    // staged truth boxes: per t: [tx, ty, minx, miny, maxx, maxy, area, atan]
    __shared__ float s_t[T_BOX * 8];
    __shared__ float s_red[4][3];

    const int b = blockIdx.y;
    const int tid = threadIdx.x;

    if (tid < T_BOX) {
        const float* yt = ytrue + ((size_t)b * T_BOX + tid) * 4;
        float tx = yt[0], ty = yt[1], tw = yt[2], th = yt[3];
        float* s = s_t + tid * 8;
        s[0] = tx; s[1] = ty;
        s[2] = tx - 0.5f * tw; s[3] = ty - 0.5f * th;
        s[4] = tx + 0.5f * tw; s[5] = ty + 0.5f * th;
        s[6] = tw * th;
        s[7] = atan2f(tw, th);
    }
    __syncthreads();

    const int ncell = H * W * 3;
    const int cell = blockIdx.x * blockDim.x + tid;

    float loc = 0.0f, conf = 0.0f, clsl = 0.0f;

    if (cell < ncell) {
        const int a  = cell % 3;
        const int hw = cell / 3;
        const int w  = hw % W;
        const int h  = hw / W;

        const float* p = pred + ((size_t)((b * H + h) * W + w)) * 255 + a * 85;

        const float aw = (a == 0) ? aw0 : ((a == 1) ? aw1 : aw2);
        const float ah = (a == 0) ? ah0 : ((a == 1) ? ah1 : ah2);

        const float px = (sigmoidf_(p[0]) + (float)w) / (float)W;
        const float py = (sigmoidf_(p[1]) + (float)h) / (float)H;
        const float pw = __expf(p[2]) * aw * INV416;
        const float ph = __expf(p[3]) * ah * INV416;

        const float pminx = px - 0.5f * pw, pminy = py - 0.5f * ph;
        const float pmaxx = px + 0.5f * pw, pmaxy = py + 0.5f * ph;
        const float parea = pw * ph;
        const float patan = atan2f(pw, ph);

        const float* m = mask + ((size_t)b * ncell + cell) * (size_t)T_BOX;

        const float c4pi2 = 4.0f / (float)(M_PI * M_PI);
        float best = 0.0f;   // iou >= 0 always
        float obj = 0.0f;
        float locsum = 0.0f;

        #pragma unroll 1
        for (int t0 = 0; t0 < T_BOX; t0 += 4) {
            const float4 mv4 = *reinterpret_cast<const float4*>(m + t0);
            #pragma unroll
            for (int j = 0; j < 4; ++j) {
                const int t = t0 + j;
                const float mv = (&mv4.x)[j];
                const float* s = s_t + t * 8;
                float iwx = fminf(s[4], pmaxx) - fmaxf(s[2], pminx);
                float iwy = fminf(s[5], pmaxy) - fmaxf(s[3], pminy);
                iwx = fmaxf(iwx, 0.0f); iwy = fmaxf(iwy, 0.0f);
                const float inter = iwx * iwy;
                const float uni = s[6] + parea - inter;
                const float iou = inter / (uni + EPSF);
                best = fmaxf(best, iou);

                const float dx = s[0] - px, dy = s[1] - py;
                const float center = dx * dx + dy * dy;
                float ewx = fmaxf(s[4], pmaxx) - fminf(s[2], pminx);
                float ewy = fmaxf(s[5], pmaxy) - fminf(s[3], pminy);
                ewx = fmaxf(ewx, 0.0f); ewy = fmaxf(ewy, 0.0f);
                const float diag = ewx * ewx + ewy * ewy;
                const float diou = iou - center / (diag + EPSF);
                const float dv = s[7] - patan;
                const float v = c4pi2 * dv * dv;
                const float alpha = v / (1.0f - iou + v + EPSF);
                const float ciou = diou - alpha * v;
                locsum += (1.0f - ciou) * mv;
                obj = fmaxf(obj, mv);
            }
        }

        // class pass: class_sum, bce sum, max logit in one sweep
        const float* cp = cls + ((size_t)b * ncell + cell) * (size_t)NCLS;
        float csum = 0.0f, bsum = 0.0f, maxlogit = -1e30f;
        #pragma unroll 1
        for (int c0 = 0; c0 < NCLS; c0 += 4) {
            const float4 z4 = *reinterpret_cast<const float4*>(cp + c0);
            #pragma unroll
            for (int j = 0; j < 4; ++j) {
                const float z = (&z4.x)[j];
                const float x = p[5 + c0 + j];
                csum += z;
                maxlogit = fmaxf(maxlogit, x);
                bsum += fmaxf(x, 0.0f) - x * z + softplus_abs_(x);
            }
        }

        const float x4 = p[4];
        const float bce_obj = fmaxf(x4, 0.0f) - x4 * obj + softplus_abs_(x4);

        const bool ignore = best < 0.5f;
        const bool ignore_match = best > 0.5f;
        const bool cid = (sigmoidf_(maxlogit) < 0.25f) && ignore_match;
        const float ignore_mask = (ignore || cid) ? 1.0f : 0.0f;

        conf = obj * bce_obj + (1.0f - obj) * bce_obj * ignore_mask;
        clsl = obj * bsum;
        const float csum2 = csum + ((csum == 0.0f) ? 1.0f : 0.0f);
        loc = locsum / csum2;
    }

    // block reduction: 4 waves of 64
    loc  = waveReduceAdd(loc);
    conf = waveReduceAdd(conf);
    clsl = waveReduceAdd(clsl);
    const int lane = tid & 63;
    const int wv = tid >> 6;
    if (lane == 0) {
        s_red[wv][0] = loc; s_red[wv][1] = conf; s_red[wv][2] = clsl;
    }
    __syncthreads();
    if (tid == 0) {
        float L = 0.0f, C = 0.0f, K = 0.0f;
        #pragma unroll
        for (int i = 0; i < 4; ++i) {
            L += s_red[i][0]; C += s_red[i][1]; K += s_red[i][2];
        }
        atomicAdd(&acc[0], L);
        atomicAdd(&acc[1], C);
        atomicAdd(&acc[2], K);
    }
}

__global__ void yolo_finalize(const float* __restrict__ acc,
                              float* __restrict__ out, float invB) {
    const float loc  = (acc[0] + acc[3]) * invB;
    const float conf = (acc[1] + acc[4]) * invB;
    const float cls  = (acc[2] + acc[5]) * invB;
    out[0] = loc + conf + cls;
    out[1] = loc;
    out[2] = conf;
    out[3] = cls;
}

extern "C" void kernel_launch(void* const* d_in, const int* in_sizes, int n_in,
                              void* d_out, int out_size, void* d_ws, size_t ws_size,
                              hipStream_t stream) {
    const float* out0  = (const float*)d_in[0];  // (B,13,13,255)
    const float* out1  = (const float*)d_in[1];  // (B,26,26,255)
    const float* ytrue = (const float*)d_in[2];  // (B,100,4)
    const float* m0    = (const float*)d_in[3];  // (B,13,13,3,100)
    const float* m1    = (const float*)d_in[4];  // (B,26,26,3,100)
    const float* c0    = (const float*)d_in[5];  // (B,13,13,3,80)
    const float* c1    = (const float*)d_in[6];  // (B,26,26,3,80)
    float* out = (float*)d_out;
    float* acc = (float*)d_ws;

    const int B = in_sizes[0] / (13 * 13 * 255);

    hipMemsetAsync(acc, 0, 6 * sizeof(float), stream);

    {
        const int H = 13, W = 13;
        const int ncell = H * W * 3;
        dim3 grid((ncell + 255) / 256, B);
        yolo_level_kernel<<<grid, 256, 0, stream>>>(
            out0, m0, c0, ytrue, acc + 0, H, W,
            81.0f, 82.0f, 135.0f, 169.0f, 344.0f, 319.0f);
    }
    {
        const int H = 26, W = 26;
        const int ncell = H * W * 3;
        dim3 grid((ncell + 255) / 256, B);
        yolo_level_kernel<<<grid, 256, 0, stream>>>(
            out1, m1, c1, ytrue, acc + 3, H, W,
            10.0f, 14.0f, 23.0f, 27.0f, 37.0f, 58.0f);
    }
    yolo_finalize<<<1, 1, 0, stream>>>(acc, out, 1.0f / (float)B);
}

// Round 3
// 101.264 us; speedup vs baseline: 1.5370x; 1.5370x over previous
//
#include <hip/hip_runtime.h>
#include <math.h>

#define T_BOX 100
#define NCLS 80
constexpr float EPSF = 1e-7f;
constexpr float INV416 = 1.0f / 416.0f;

__device__ __forceinline__ float rcpf_(float x) { return __builtin_amdgcn_rcpf(x); }
__device__ __forceinline__ float sigmoidf_(float x) { return rcpf_(1.0f + __expf(-x)); }
__device__ __forceinline__ float softplus_abs_(float x) {
    // log1p(exp(-|x|)) ; fast: abs err ~ulp, fine vs 2% threshold
    return __logf(1.0f + __expf(-fabsf(x)));
}

// anchors[level][anchor][wh]; level 0 = 13x13 (mask 3,4,5), level 1 = 26x26 (mask 0,1,2)
__constant__ float c_anc[2][3][2] = {
    {{81.0f, 82.0f}, {135.0f, 169.0f}, {344.0f, 319.0f}},
    {{10.0f, 14.0f}, {23.0f, 27.0f}, {37.0f, 58.0f}},
};

#define NBLK0 4   // ceil(13*13*3*2 / 256)
#define NBLK1 16  // ceil(26*26*3*2 / 256)

__device__ __forceinline__ float waveReduceAdd(float v) {
    #pragma unroll
    for (int o = 32; o > 0; o >>= 1) v += __shfl_down(v, o);
    return v;
}

// Two threads per cell; fused both levels. Grid: (NBLK0+NBLK1, B).
__global__ __launch_bounds__(256) void yolo_fused_kernel(
    const float* __restrict__ pred0, const float* __restrict__ mask0, const float* __restrict__ cls0,
    const float* __restrict__ pred1, const float* __restrict__ mask1, const float* __restrict__ cls1,
    const float* __restrict__ ytrue,
    float* __restrict__ acc)  // 6 floats: [loc0,conf0,cls0, loc1,conf1,cls1]
{
    // staged truth boxes: per t: {tx,ty,minx,miny}, {maxx,maxy,area,atan}
    __shared__ float4 s_t[T_BOX][2];
    __shared__ float s_red[4][3];

    const int b = blockIdx.y;
    const int tid = threadIdx.x;

    if (tid < T_BOX) {
        const float* yt = ytrue + ((size_t)b * T_BOX + tid) * 4;
        const float tx = yt[0], ty = yt[1], tw = yt[2], th = yt[3];
        s_t[tid][0] = make_float4(tx, ty, tx - 0.5f * tw, ty - 0.5f * th);
        s_t[tid][1] = make_float4(tx + 0.5f * tw, ty + 0.5f * th, tw * th, atan2f(tw, th));
    }
    __syncthreads();

    int level, W, H, lb;
    float invW, invH;
    const float *pred, *mask, *cls;
    float* accl;
    if (blockIdx.x < NBLK0) {
        level = 0; W = 13; H = 13; lb = (int)blockIdx.x;
        invW = 1.0f / 13.0f; invH = 1.0f / 13.0f;
        pred = pred0; mask = mask0; cls = cls0; accl = acc;
    } else {
        level = 1; W = 26; H = 26; lb = (int)blockIdx.x - NBLK0;
        invW = 1.0f / 26.0f; invH = 1.0f / 26.0f;
        pred = pred1; mask = mask1; cls = cls1; accl = acc + 3;
    }

    const int ncell = H * W * 3;
    const int idx = lb * 256 + tid;
    const int cell = idx >> 1;   // pair of threads per cell
    const int sub = idx & 1;

    float loc = 0.0f, conf = 0.0f, clsl = 0.0f;

    if (cell < ncell) {
        const int a  = cell % 3;
        const int hw = cell / 3;
        const int w  = hw % W;
        const int h  = hw / W;

        const float* p = pred + ((size_t)((b * H + h) * W + w)) * 255 + a * 85;

        const float aw = c_anc[level][a][0];
        const float ah = c_anc[level][a][1];

        const float px = (sigmoidf_(p[0]) + (float)w) * invW;
        const float py = (sigmoidf_(p[1]) + (float)h) * invH;
        const float pw = __expf(p[2]) * aw * INV416;
        const float ph = __expf(p[3]) * ah * INV416;

        const float pminx = px - 0.5f * pw, pminy = py - 0.5f * ph;
        const float pmaxx = px + 0.5f * pw, pmaxy = py + 0.5f * ph;
        const float parea = pw * ph;
        const float patan = atan2f(pw, ph);

        const float* m = mask + ((size_t)b * ncell + cell) * (size_t)T_BOX;

        const float c4pi2 = 4.0f / (float)(M_PI * M_PI);
        float best = 0.0f;   // iou >= 0 always
        float obj = 0.0f;
        float locsum = 0.0f;

        // alternate aligned float4 chunks between the two pair-threads
        #pragma unroll 1
        for (int t0 = 4 * sub; t0 < T_BOX; t0 += 8) {
            const float4 mv4 = *reinterpret_cast<const float4*>(m + t0);
            #pragma unroll
            for (int j = 0; j < 4; ++j) {
                const int t = t0 + j;
                const float mv = (&mv4.x)[j];
                const float4 s0 = s_t[t][0];   // tx,ty,minx,miny
                const float4 s1 = s_t[t][1];   // maxx,maxy,area,atan
                float iwx = fminf(s1.x, pmaxx) - fmaxf(s0.z, pminx);
                float iwy = fminf(s1.y, pmaxy) - fmaxf(s0.w, pminy);
                iwx = fmaxf(iwx, 0.0f); iwy = fmaxf(iwy, 0.0f);
                const float inter = iwx * iwy;
                const float uni = s1.z + parea - inter;
                const float iou = inter * rcpf_(uni + EPSF);
                best = fmaxf(best, iou);

                const float dx = s0.x - px, dy = s0.y - py;
                const float center = dx * dx + dy * dy;
                float ewx = fmaxf(s1.x, pmaxx) - fminf(s0.z, pminx);
                float ewy = fmaxf(s1.y, pmaxy) - fminf(s0.w, pminy);
                ewx = fmaxf(ewx, 0.0f); ewy = fmaxf(ewy, 0.0f);
                const float diag = ewx * ewx + ewy * ewy;
                const float diou = iou - center * rcpf_(diag + EPSF);
                const float dv = s1.w - patan;
                const float v = c4pi2 * dv * dv;
                const float alpha = v * rcpf_(1.0f - iou + v + EPSF);
                const float ciou = diou - alpha * v;
                locsum += (1.0f - ciou) * mv;
                obj = fmaxf(obj, mv);
            }
        }

        // class pass: class_sum, bce sum, max logit; alternate float4 chunks
        const float* cp = cls + ((size_t)b * ncell + cell) * (size_t)NCLS;
        float csum = 0.0f, bsum = 0.0f, maxlogit = -1e30f;
        #pragma unroll 1
        for (int c0 = 4 * sub; c0 < NCLS; c0 += 8) {
            const float4 z4 = *reinterpret_cast<const float4*>(cp + c0);
            #pragma unroll
            for (int j = 0; j < 4; ++j) {
                const float z = (&z4.x)[j];
                const float x = p[5 + c0 + j];
                csum += z;
                maxlogit = fmaxf(maxlogit, x);
                bsum += fmaxf(x, 0.0f) - x * z + softplus_abs_(x);
            }
        }

        // pair combine (partner lane = lane^1, same cell)
        locsum  += __shfl_xor(locsum, 1);
        best     = fmaxf(best, __shfl_xor(best, 1));
        obj      = fmaxf(obj, __shfl_xor(obj, 1));
        csum    += __shfl_xor(csum, 1);
        bsum    += __shfl_xor(bsum, 1);
        maxlogit = fmaxf(maxlogit, __shfl_xor(maxlogit, 1));

        if (sub == 0) {
            const float x4 = p[4];
            const float bce_obj = fmaxf(x4, 0.0f) - x4 * obj + softplus_abs_(x4);

            const bool ignore = best < 0.5f;
            const bool ignore_match = best > 0.5f;
            const bool cid = (sigmoidf_(maxlogit) < 0.25f) && ignore_match;
            const float ignore_mask = (ignore || cid) ? 1.0f : 0.0f;

            conf = obj * bce_obj + (1.0f - obj) * bce_obj * ignore_mask;
            clsl = obj * bsum;
            const float csum2 = csum + ((csum == 0.0f) ? 1.0f : 0.0f);
            loc = locsum * rcpf_(csum2);
        }
    }

    // block reduction: 4 waves of 64
    loc  = waveReduceAdd(loc);
    conf = waveReduceAdd(conf);
    clsl = waveReduceAdd(clsl);
    const int lane = tid & 63;
    const int wv = tid >> 6;
    if (lane == 0) {
        s_red[wv][0] = loc; s_red[wv][1] = conf; s_red[wv][2] = clsl;
    }
    __syncthreads();
    if (tid == 0) {
        float L = 0.0f, C = 0.0f, K = 0.0f;
        #pragma unroll
        for (int i = 0; i < 4; ++i) {
            L += s_red[i][0]; C += s_red[i][1]; K += s_red[i][2];
        }
        atomicAdd(&accl[0], L);
        atomicAdd(&accl[1], C);
        atomicAdd(&accl[2], K);
    }
}

__global__ void yolo_finalize(const float* __restrict__ acc,
                              float* __restrict__ out, float invB) {
    const float loc  = (acc[0] + acc[3]) * invB;
    const float conf = (acc[1] + acc[4]) * invB;
    const float cls  = (acc[2] + acc[5]) * invB;
    out[0] = loc + conf + cls;
    out[1] = loc;
    out[2] = conf;
    out[3] = cls;
}

extern "C" void kernel_launch(void* const* d_in, const int* in_sizes, int n_in,
                              void* d_out, int out_size, void* d_ws, size_t ws_size,
                              hipStream_t stream) {
    const float* out0  = (const float*)d_in[0];  // (B,13,13,255)
    const float* out1  = (const float*)d_in[1];  // (B,26,26,255)
    const float* ytrue = (const float*)d_in[2];  // (B,100,4)
    const float* m0    = (const float*)d_in[3];  // (B,13,13,3,100)
    const float* m1    = (const float*)d_in[4];  // (B,26,26,3,100)
    const float* c0    = (const float*)d_in[5];  // (B,13,13,3,80)
    const float* c1    = (const float*)d_in[6];  // (B,26,26,3,80)
    float* out = (float*)d_out;
    float* acc = (float*)d_ws;

    const int B = in_sizes[0] / (13 * 13 * 255);

    hipMemsetAsync(acc, 0, 6 * sizeof(float), stream);

    dim3 grid(NBLK0 + NBLK1, B);
    yolo_fused_kernel<<<grid, 256, 0, stream>>>(
        out0, m0, c0, out1, m1, c1, ytrue, acc);

    yolo_finalize<<<1, 1, 0, stream>>>(acc, out, 1.0f / (float)B);
}